// Round 1
// baseline (875.232 us; speedup 1.0000x reference)
//
#include <hip/hip_runtime.h>
#include <math.h>

// EmmaAttention forward: out = his_x * (p/t) + x * (q/t), per (n,h) row.
//   beta = clip(1 - inv_w*agg_n[n], 0, 1)
//   mm   = max(max_a, his_m)
//   p    = exp(his_m - mm) * beta   (NaN -> exp(-inf)=0)
//   q    = exp(max_a - mm)          (NaN -> 0)
//   t    = max(p + q, 1.0)
// Memory-bound: ~1.24 GB moved per call. One thread per float4 (16B/lane).

#define N_ROWS   1600000   // N*H = 200000*8
#define VEC_PER_ROW 16     // D/4 = 64/4
#define TOTAL_V4 (N_ROWS * VEC_PER_ROW)  // 25,600,000

__global__ __launch_bounds__(256) void emma_fwd_kernel(
    const float* __restrict__ x,
    const float* __restrict__ max_a,
    const float* __restrict__ his_x,
    const float* __restrict__ his_m,
    const float* __restrict__ agg_n,
    const float* __restrict__ inv_w,
    float* __restrict__ out)
{
    int tid = blockIdx.x * blockDim.x + threadIdx.x;
    if (tid >= TOTAL_V4) return;

    int row = tid >> 4;        // n*H + h
    int n   = row >> 3;        // H = 8

    float ma = max_a[row];
    float hm = his_m[row];
    float an = agg_n[n];
    float iw = inv_w[0];       // uniform -> s_load

    float beta = 1.0f - iw * an;
    beta = fminf(fmaxf(beta, 0.0f), 1.0f);

    float mm = fmaxf(ma, hm);
    float dp = hm - mm;
    float dq = ma - mm;
    // jnp.nan_to_num(diff, nan=-inf) -> exp becomes 0 on NaN
    float p = isnan(dp) ? 0.0f : expf(dp);
    float q = isnan(dq) ? 0.0f : expf(dq);
    p *= beta;

    float t = p + q;
    t = fmaxf(t, 1.0f);
    float rt = 1.0f / t;
    p *= rt;
    q *= rt;

    const float4* __restrict__ x4  = reinterpret_cast<const float4*>(x);
    const float4* __restrict__ hx4 = reinterpret_cast<const float4*>(his_x);
    float4*       __restrict__ o4  = reinterpret_cast<float4*>(out);

    float4 xv = x4[tid];
    float4 hv = hx4[tid];
    float4 ov;
    ov.x = hv.x * p + xv.x * q;
    ov.y = hv.y * p + xv.y * q;
    ov.z = hv.z * p + xv.z * q;
    ov.w = hv.w * p + xv.w * q;
    o4[tid] = ov;
}

extern "C" void kernel_launch(void* const* d_in, const int* in_sizes, int n_in,
                              void* d_out, int out_size, void* d_ws, size_t ws_size,
                              hipStream_t stream) {
    const float* x     = (const float*)d_in[0];
    const float* max_a = (const float*)d_in[1];
    const float* his_x = (const float*)d_in[2];
    const float* his_m = (const float*)d_in[3];
    const float* agg_n = (const float*)d_in[4];
    const float* inv_w = (const float*)d_in[5];
    float* out = (float*)d_out;

    const int block = 256;
    const int grid  = (TOTAL_V4 + block - 1) / block;   // 100,000 blocks
    emma_fwd_kernel<<<grid, block, 0, stream>>>(x, max_a, his_x, his_m,
                                                agg_n, inv_w, out);
}